// Round 2
// baseline (223.284 us; speedup 1.0000x reference)
//
#include <hip/hip_runtime.h>
#include <hip/hip_bf16.h>
#include <stdint.h>

// Problem constants
#define Bn   32
#define CIN  128
#define Hh   56
#define Ww   56
#define COUT 256
#define HP   58            // padded rows (1 top + 1 bottom)
#define WP   58            // padded width: 0=pad, 1..56 data, 57=pad (PROVEN 28.1MB ws footprint)
#define ROWB (WP*CIN)      // 7424 elements per padded row
#define NCHUNK 36          // K chunks of 32, order kt = hf*18 + kh*6 + kw*2 + c

// prep kernel block partition (all write-disjoint regions, single launch)
#define DATA_BLKS (Bn*Hh)                 // 1792: one (b,h) data row each
#define ZERO_BLKS (Bn)                    // 32: pad rows + side pad columns
#define WT_BLKS   96                      // (mb,hf,kh): 16*2*3 weight slabs
#define PREP_GRID (DATA_BLKS + ZERO_BLKS + WT_BLKS)

typedef __attribute__((ext_vector_type(8))) short short8;     // 8 x bf16
typedef __attribute__((ext_vector_type(4))) float floatx4;

__device__ __forceinline__ void async_copy16(const void* g, void* l) {
  // global -> LDS direct copy: GLOBAL address is PER-LANE (supply lane-dependent
  // pointer!); LDS dest = wave-uniform base + lane*16.  [m104/m108]
  __builtin_amdgcn_global_load_lds(
      (const __attribute__((address_space(1))) uint32_t*)g,
      (__attribute__((address_space(3))) uint32_t*)l, 16, 0, 0);
}

__device__ __forceinline__ uint32_t pk2(float a, float b) {
  // pack two fp32 -> (bf16(a) | bf16(b)<<16), RNE via __float2bfloat16
  union { __hip_bfloat16 h; unsigned short u; } ca, cb;
  ca.h = __float2bfloat16(a);
  cb.h = __float2bfloat16(b);
  return (uint32_t)ca.u | ((uint32_t)cb.u << 16);
}

// ---------------------------------------------------------------------------
// prep: single launch replacing xform_x + xform_w (R1-verified, unchanged).
//   blocks [0,1792): x NCHW fp32 -> NHWC bf16 data cells
//   blocks [1792,1824): zero ONLY the pad cells of xp
//   blocks [1824,1920): w OIHW fp32 -> fragment-ordered wtf via LDS slab
// ---------------------------------------------------------------------------
__global__ __launch_bounds__(256) void prep(const float* __restrict__ x,
                                            const float* __restrict__ w,
                                            __hip_bfloat16* __restrict__ xp,
                                            __hip_bfloat16* __restrict__ wtf) {
  __shared__ uint32_t t[HP * 65];   // 15080 B; weight path aliases as float[]
  const int bid = blockIdx.x, tid = threadIdx.x;

  if (bid < DATA_BLKS) {
    const int b = bid / Hh, h = bid % Hh;
    const float* xrow = x + (size_t)b * (CIN * Hh * Ww) + (size_t)h * Ww;
    for (int i = tid; i < 1024; i += 256) {
      const int wq = i & 15, cp = i >> 4;
      if (wq < 14) {
        const float* g0 = xrow + (size_t)(2 * cp) * (Hh * Ww) + wq * 4;
        const float4 v0 = *(const float4*)g0;
        const float4 v1 = *(const float4*)(g0 + Hh * Ww);
        const int r0 = (1 + 4 * wq) * 65 + cp;
        t[r0      ] = pk2(v0.x, v1.x);
        t[r0 +  65] = pk2(v0.y, v1.y);
        t[r0 + 130] = pk2(v0.z, v1.z);
        t[r0 + 195] = pk2(v0.w, v1.w);
      }
    }
    __syncthreads();
    const size_t obase = ((size_t)b * HP + (h + 1)) * ROWB;
    for (int i = tid; i < 896; i += 256) {
      const int wo = 1 + (i >> 4), cq = i & 15;
      const uint32_t* s = &t[wo * 65 + cq * 4];
      uint4 d; d.x = s[0]; d.y = s[1]; d.z = s[2]; d.w = s[3];
      *(uint4*)(xp + obase + (size_t)wo * CIN + cq * 8) = d;
    }
  } else if (bid < DATA_BLKS + ZERO_BLKS) {
    const int b = bid - DATA_BLKS;
    const uint4 z = {0u, 0u, 0u, 0u};
    uint4* r0  = (uint4*)(xp + (size_t)b * HP * ROWB);
    uint4* r57 = (uint4*)(xp + ((size_t)b * HP + (HP - 1)) * ROWB);
    for (int i = tid; i < ROWB / 8; i += 256) { r0[i] = z; r57[i] = z; }
    for (int i = tid; i < Hh * 32; i += 256) {      // 56 rows x (16+16) uint4
      const int hp = 1 + (i >> 5), s5 = i & 31;
      uint4* pr = (uint4*)(xp + ((size_t)b * HP + hp) * ROWB);
      pr[s5 < 16 ? s5 : (912 + s5 - 16)] = z;       // 912 = 57*128*2/16
    }
  } else {
    const int widx = bid - (DATA_BLKS + ZERO_BLKS);
    const int mb = widx / 6, t6 = widx % 6, hf = t6 / 3, kh = t6 % 3;
    float* s = (float*)t;                            // 3072 floats = 12 KB
    const float* wbase = w + (size_t)(mb * 16) * (CIN * 9) + hf * 576 + kh * 3;
    for (int idx = tid; idx < 3072; idx += 256) {    // s[m'][ci'][kw]
      const int mp = idx / 192, r2 = idx - mp * 192;
      const int cip = r2 / 3, p = r2 - cip * 3;
      s[idx] = wbase[(size_t)mp * (CIN * 9) + cip * 9 + p];
    }
    __syncthreads();
    uint32_t* wtfU = (uint32_t*)wtf;
    for (int k = 0; k < 6; ++k) {                    // 6 kt values: r = kw*2+c
      const int u = tid + k * 256;
      const int r = u >> 8, lane = (u >> 2) & 63, ep = u & 3;
      const int kw = r >> 1, c = r & 1;
      const int kt = hf * 18 + kh * 6 + r;
      const int fm = lane & 15, q = lane >> 4;
      const int cb = c * 32 + q * 8 + 2 * ep;        // ci' of even element
      const float v0 = s[fm * 192 + cb * 3 + kw];
      const float v1 = s[fm * 192 + (cb + 1) * 3 + kw];
      wtfU[(size_t)(kt * 16 + mb) * 256 + lane * 4 + ep] = pk2(v0, v1);
    }
  }
}

// ---------------------------------------------------------------------------
// Conv GEMM — R2: depth-2 counted-vmcnt pipeline (T4-lite) + conflict-free
// B-read swizzle (T2, both-sides: pre-swizzled global src + lane-const read).
//   128x128 tile, 4 waves x (4x4 of 16x16x32 bf16). BK=32, 36 iters.
//   THREE LDS buffers (48KB): iter t reads buf[t%3], stages tile t+2 into
//   buf[(t+2)%3]. Wait = s_waitcnt vmcnt(4) (tile t landed; tile t+1's 4
//   loads may stay in flight) + raw s_barrier. Tail (t=35) uses vmcnt(0).
//   Race-free: buf[(t+2)%3]'s last readers (iter t-1) retired their ds_reads
//   before the iter-t barrier; vmcnt retires in issue order [m135].
//   3 blocks/CU x 48KB = 144KB LDS.
// ---------------------------------------------------------------------------
__global__ __launch_bounds__(256, 3) void conv_gemm(const __hip_bfloat16* __restrict__ wtf,
                                                    const __hip_bfloat16* __restrict__ xp,
                                                    const float* __restrict__ bias,
                                                    float* __restrict__ y) {
  __shared__ __align__(16) char Ab[3][8192];   // [buf][mb' 0..7][lane][16B]
  __shared__ __align__(16) char Bb[3][8192];   // [buf][pixel 0..127][64B swizzled]

  const int tid  = threadIdx.x;
  const int lane = tid & 63, wv = tid >> 6;
  const int fm = lane & 15, q = lane >> 4;
  const int waveM = wv & 1, waveN = wv >> 1;
  // T2 read-side swizzle: 16B-unit index q ^ ((fm>>1)&3) (row base %16==0 ->
  // key reduces to fm bits). Banks: 16*(fm&1)+4*(q^((fm>>1)&3)) -> 2 lanes/slot.
  const int qx16 = (q ^ ((fm >> 1) & 3)) * 16;

  // XCD swizzle: gid, gid+8 share bn (same B tile) on one XCD. Bijective/1568.
  const int gid = blockIdx.x;
  const int bm = (gid >> 3) & 1;
  const int bn = (gid & 7) | ((gid >> 4) << 3);   // [0,784)
  const int m0 = bm * 128, n0 = bn * 128;

  // ---- A staging source: PER-LANE address.
  const char* aSrc = (const char*)wtf + (size_t)bm * 8192 + wv * 2048 + lane * 16;

  // ---- B staging sources: 2 pixel-groups of 16 per wave. T2 write-side:
  // swizzle the GLOBAL 16B-unit by ((lane>>3)&3) = ((r>>1)&3) for LDS row
  // r = lane>>2; LDS dest stays linear (global_load_lds requirement, m104).
  const __hip_bfloat16* bSrc[2];
#pragma unroll
  for (int c = 0; c < 2; ++c) {
    const int sr = wv * 32 + c * 16 + (lane >> 2);     // pixel row in tile
    const int n_r = n0 + sr;
    const int b = n_r / 3136, r = n_r - b * 3136, h = r / 56, w = r - h * 56;
    const int c16 = (lane & 3) ^ ((lane >> 3) & 3);    // swizzled 16B unit
    bSrc[c] = xp + (size_t)((b * HP + h) * WP + w) * CIN + c16 * 8;
  }

  floatx4 acc[4][4];
#pragma unroll
  for (int i = 0; i < 4; ++i)
#pragma unroll
    for (int j = 0; j < 4; ++j) acc[i][j] = (floatx4){0.f, 0.f, 0.f, 0.f};

#define STAGE(KT, BUF)                                                          \
  do {                                                                          \
    const int _kt = (KT);                                                       \
    const int _rem = _kt % 18, _kh = _rem / 6, _r2 = _rem % 6;                  \
    const int _kw = _r2 >> 1, _ci0 = (_kt / 18) * 64 + (_r2 & 1) * 32;          \
    const int _bOff = (_kh * WP + _kw) * CIN + _ci0;                            \
    async_copy16(aSrc + (size_t)_kt * 16384, Ab[BUF] + wv * 2048);              \
    async_copy16(aSrc + (size_t)_kt * 16384 + 1024, Ab[BUF] + wv * 2048 + 1024);\
    async_copy16(bSrc[0] + _bOff, Bb[BUF] + wv * 2048);                         \
    async_copy16(bSrc[1] + _bOff, Bb[BUF] + wv * 2048 + 1024);                  \
  } while (0)

  // COMPUTE(t): wait (tile t landed, tile t+1 may fly), barrier, optional
  // stage of tile t+2, then ds-reads + 16 MFMA on buf[t%3].
#define COMPUTE(T, DOSTAGE, VM4)                                                \
  do {                                                                          \
    if (VM4) asm volatile("s_waitcnt vmcnt(4)" ::: "memory");                   \
    else     asm volatile("s_waitcnt vmcnt(0)" ::: "memory");                   \
    __builtin_amdgcn_s_barrier();                                               \
    __builtin_amdgcn_sched_barrier(0);                                          \
    if (DOSTAGE) STAGE((T) + 2, ((T) + 2) % 3);                                 \
    const int _buf = (T) % 3;                                                   \
    short8 a[4], b[4];                                                          \
    _Pragma("unroll")                                                           \
    for (int i = 0; i < 4; ++i)                                                 \
      a[i] = *(const short8*)(Ab[_buf] + (waveM * 4 + i) * 1024 + lane * 16);   \
    _Pragma("unroll")                                                           \
    for (int j = 0; j < 4; ++j)                                                 \
      b[j] = *(const short8*)(Bb[_buf] + (waveN * 64 + j * 16 + fm) * 64 + qx16);\
    _Pragma("unroll")                                                           \
    for (int i = 0; i < 4; ++i)                                                 \
      _Pragma("unroll")                                                         \
      for (int j = 0; j < 4; ++j)                                               \
        acc[i][j] = __builtin_amdgcn_mfma_f32_16x16x32_bf16(a[i], b[j], acc[i][j], 0, 0, 0); \
  } while (0)

  STAGE(0, 0);   // prologue: tiles 0,1 in flight (8 loads/thread)
  STAGE(1, 1);

#pragma unroll 3
  for (int kt = 0; kt < 33; ++kt) {     // stages tiles 2..34
    COMPUTE(kt, 1, 1);
  }
  COMPUTE(33, 1, 1);                    // stages tile 35 (last stage)
  COMPUTE(34, 0, 1);                    // outstanding = tile35's 4 -> newest-4 ok
  COMPUTE(35, 0, 0);                    // full drain: tile 35 must be landed
#undef COMPUTE
#undef STAGE

  // ---- epilogue: D col = lane&15 (n), row = (lane>>4)*4 + reg (m)
  const int col = lane & 15, quad = lane >> 4;
#pragma unroll
  for (int j = 0; j < 4; ++j) {
    const int n = n0 + waveN * 64 + j * 16 + col;
    const int bb = n / 3136, nr = n - bb * 3136;
    const size_t base = (size_t)bb * (COUT * 3136) + nr;
#pragma unroll
    for (int i = 0; i < 4; ++i) {
      const int co0 = m0 + waveM * 64 + i * 16 + quad * 4;
      const floatx4 b4 = *(const floatx4*)&bias[co0];
#pragma unroll
      for (int r = 0; r < 4; ++r) {
        y[base + (size_t)(co0 + r) * 3136] = acc[i][j][r] + b4[r];
      }
    }
  }
}

extern "C" void kernel_launch(void* const* d_in, const int* in_sizes, int n_in,
                              void* d_out, int out_size, void* d_ws, size_t ws_size,
                              hipStream_t stream) {
  const float* x = (const float*)d_in[0];
  const float* w = (const float*)d_in[1];
  const float* b = (const float*)d_in[2];
  float* y = (float*)d_out;

  // ws footprint: 27,541,504 + 589,824 = 28,131,328 B — identical to prior rounds
  const size_t xpad_bytes = (size_t)Bn * HP * ROWB * sizeof(__hip_bfloat16);
  __hip_bfloat16* xp  = (__hip_bfloat16*)d_ws;
  __hip_bfloat16* wtf = (__hip_bfloat16*)((char*)d_ws + xpad_bytes);

  prep<<<PREP_GRID, 256, 0, stream>>>(x, w, xp, wtf);
  conv_gemm<<<2 * ((Bn * Hh * Ww) / 128), 256, 0, stream>>>(wtf, xp, b, y);
}

// Round 4
// 210.367 us; speedup vs baseline: 1.0614x; 1.0614x over previous
//
#include <hip/hip_runtime.h>
#include <hip/hip_bf16.h>
#include <stdint.h>

// Problem constants
#define Bn   32
#define CIN  128
#define Hh   56
#define Ww   56
#define COUT 256
#define HP   58            // padded rows (1 top + 1 bottom)
#define WP   58            // padded width: 0=pad, 1..56 data, 57=pad (PROVEN 28.1MB ws footprint)
#define ROWB (WP*CIN)      // 7424 elements per padded row
#define NCHUNK 36          // K chunks of 32, order kt = hf*18 + kh*6 + kw*2 + c

// prep kernel block partition (all write-disjoint regions, single launch)
#define DATA_BLKS (Bn*Hh)                 // 1792: one (b,h) data row each
#define ZERO_BLKS (Bn)                    // 32: pad rows + side pad columns
#define WT_BLKS   96                      // (mb,hf,kh): 16*2*3 weight slabs
#define PREP_GRID (DATA_BLKS + ZERO_BLKS + WT_BLKS)

typedef __attribute__((ext_vector_type(8))) short short8;     // 8 x bf16
typedef __attribute__((ext_vector_type(4))) float floatx4;

__device__ __forceinline__ void async_copy16(const void* g, void* l) {
  // global -> LDS direct copy: GLOBAL address is PER-LANE (supply lane-dependent
  // pointer!); LDS dest = wave-uniform base + lane*16.  [m104/m108]
  __builtin_amdgcn_global_load_lds(
      (const __attribute__((address_space(1))) uint32_t*)g,
      (__attribute__((address_space(3))) uint32_t*)l, 16, 0, 0);
}

__device__ __forceinline__ uint32_t pk2(float a, float b) {
  // pack two fp32 -> (bf16(a) | bf16(b)<<16), RNE via __float2bfloat16
  union { __hip_bfloat16 h; unsigned short u; } ca, cb;
  ca.h = __float2bfloat16(a);
  cb.h = __float2bfloat16(b);
  return (uint32_t)ca.u | ((uint32_t)cb.u << 16);
}

// ---------------------------------------------------------------------------
// prep: single launch replacing xform_x + xform_w (R1-verified, unchanged).
//   blocks [0,1792): x NCHW fp32 -> NHWC bf16 data cells
//   blocks [1792,1824): zero ONLY the pad cells of xp
//   blocks [1824,1920): w OIHW fp32 -> fragment-ordered wtf via LDS slab
// ---------------------------------------------------------------------------
__global__ __launch_bounds__(256) void prep(const float* __restrict__ x,
                                            const float* __restrict__ w,
                                            __hip_bfloat16* __restrict__ xp,
                                            __hip_bfloat16* __restrict__ wtf) {
  __shared__ uint32_t t[HP * 65];   // 15080 B; weight path aliases as float[]
  const int bid = blockIdx.x, tid = threadIdx.x;

  if (bid < DATA_BLKS) {
    const int b = bid / Hh, h = bid % Hh;
    const float* xrow = x + (size_t)b * (CIN * Hh * Ww) + (size_t)h * Ww;
    for (int i = tid; i < 1024; i += 256) {
      const int wq = i & 15, cp = i >> 4;
      if (wq < 14) {
        const float* g0 = xrow + (size_t)(2 * cp) * (Hh * Ww) + wq * 4;
        const float4 v0 = *(const float4*)g0;
        const float4 v1 = *(const float4*)(g0 + Hh * Ww);
        const int r0 = (1 + 4 * wq) * 65 + cp;
        t[r0      ] = pk2(v0.x, v1.x);
        t[r0 +  65] = pk2(v0.y, v1.y);
        t[r0 + 130] = pk2(v0.z, v1.z);
        t[r0 + 195] = pk2(v0.w, v1.w);
      }
    }
    __syncthreads();
    const size_t obase = ((size_t)b * HP + (h + 1)) * ROWB;
    for (int i = tid; i < 896; i += 256) {
      const int wo = 1 + (i >> 4), cq = i & 15;
      const uint32_t* s = &t[wo * 65 + cq * 4];
      uint4 d; d.x = s[0]; d.y = s[1]; d.z = s[2]; d.w = s[3];
      *(uint4*)(xp + obase + (size_t)wo * CIN + cq * 8) = d;
    }
  } else if (bid < DATA_BLKS + ZERO_BLKS) {
    const int b = bid - DATA_BLKS;
    const uint4 z = {0u, 0u, 0u, 0u};
    uint4* r0  = (uint4*)(xp + (size_t)b * HP * ROWB);
    uint4* r57 = (uint4*)(xp + ((size_t)b * HP + (HP - 1)) * ROWB);
    for (int i = tid; i < ROWB / 8; i += 256) { r0[i] = z; r57[i] = z; }
    for (int i = tid; i < Hh * 32; i += 256) {      // 56 rows x (16+16) uint4
      const int hp = 1 + (i >> 5), s5 = i & 31;
      uint4* pr = (uint4*)(xp + ((size_t)b * HP + hp) * ROWB);
      pr[s5 < 16 ? s5 : (912 + s5 - 16)] = z;       // 912 = 57*128*2/16
    }
  } else {
    const int widx = bid - (DATA_BLKS + ZERO_BLKS);
    const int mb = widx / 6, t6 = widx % 6, hf = t6 / 3, kh = t6 % 3;
    float* s = (float*)t;                            // 3072 floats = 12 KB
    const float* wbase = w + (size_t)(mb * 16) * (CIN * 9) + hf * 576 + kh * 3;
    for (int idx = tid; idx < 3072; idx += 256) {    // s[m'][ci'][kw]
      const int mp = idx / 192, r2 = idx - mp * 192;
      const int cip = r2 / 3, p = r2 - cip * 3;
      s[idx] = wbase[(size_t)mp * (CIN * 9) + cip * 9 + p];
    }
    __syncthreads();
    uint32_t* wtfU = (uint32_t*)wtf;
    for (int k = 0; k < 6; ++k) {                    // 6 kt values: r = kw*2+c
      const int u = tid + k * 256;
      const int r = u >> 8, lane = (u >> 2) & 63, ep = u & 3;
      const int kw = r >> 1, c = r & 1;
      const int kt = hf * 18 + kh * 6 + r;
      const int fm = lane & 15, q = lane >> 4;
      const int cb = c * 32 + q * 8 + 2 * ep;        // ci' of even element
      const float v0 = s[fm * 192 + cb * 3 + kw];
      const float v1 = s[fm * 192 + (cb + 1) * 3 + kw];
      wtfU[(size_t)(kt * 16 + mb) * 256 + lane * 4 + ep] = pk2(v0, v1);
    }
  }
}

// ---------------------------------------------------------------------------
// Conv GEMM — R3 (resubmit; R3 bench was an infra timeout, never ran):
// proven 78.5us 2-buffer __syncthreads structure
// (R2's raw-barrier/vmcnt graft hit the m141/m232 failure mode: 96.4us).
// Kept from R2 (verified): T2 both-sides B swizzle -> SQ_LDS_BANK_CONFLICT=0.
// New lever: __launch_bounds__(256,5) -> 5 blocks/CU (was 3). LDS 32KB x5 =
// 160KB fits; VGPR 60 <= 512/5=102 cap. Mechanism: the per-block barrier
// drain (~20-25% of 2-phase critical path, m233) is hidden by OTHER resident
// blocks (m114); 3->5 blocks raises that overlap capacity 1.67x.
//   128x128 tile, 4 waves x (4x4 of 16x16x32 bf16). BK=32, 36 iters,
//   ONE barrier per iter; stage(kt+1) issued before MFMA(kt).
// ---------------------------------------------------------------------------
__global__ __launch_bounds__(256, 5) void conv_gemm(const __hip_bfloat16* __restrict__ wtf,
                                                    const __hip_bfloat16* __restrict__ xp,
                                                    const float* __restrict__ bias,
                                                    float* __restrict__ y) {
  __shared__ __align__(16) char Ab[2][8192];   // [buf][mb' 0..7][lane][16B]
  __shared__ __align__(16) char Bb[2][8192];   // [buf][pixel 0..127][64B swizzled]

  const int tid  = threadIdx.x;
  const int lane = tid & 63, wv = tid >> 6;
  const int fm = lane & 15, q = lane >> 4;
  const int waveM = wv & 1, waveN = wv >> 1;
  // T2 read-side swizzle (R2-verified, conflicts=0): 16B-unit q ^ ((fm>>1)&3).
  // HW phases ds_read_b128 by lane groups of 16; within a phase this spreads
  // the 16 lanes across all 32 banks at 2/bank-group (free, m136).
  const int qx16 = (q ^ ((fm >> 1) & 3)) * 16;

  // XCD swizzle: gid, gid+8 share bn (same B tile) on one XCD. Bijective/1568.
  const int gid = blockIdx.x;
  const int bm = (gid >> 3) & 1;
  const int bn = (gid & 7) | ((gid >> 4) << 3);   // [0,784)
  const int m0 = bm * 128, n0 = bn * 128;

  // ---- A staging source: PER-LANE address.
  const char* aSrc = (const char*)wtf + (size_t)bm * 8192 + wv * 2048 + lane * 16;

  // ---- B staging sources: 2 pixel-groups of 16 per wave. T2 write-side
  // (R2-verified): swizzle the GLOBAL 16B-unit by ((lane>>3)&3); LDS dest
  // stays linear (global_load_lds requirement, m104). Same involution as read.
  const __hip_bfloat16* bSrc[2];
#pragma unroll
  for (int c = 0; c < 2; ++c) {
    const int sr = wv * 32 + c * 16 + (lane >> 2);     // pixel row in tile
    const int n_r = n0 + sr;
    const int b = n_r / 3136, r = n_r - b * 3136, h = r / 56, w = r - h * 56;
    const int c16 = (lane & 3) ^ ((lane >> 3) & 3);    // swizzled 16B unit
    bSrc[c] = xp + (size_t)((b * HP + h) * WP + w) * CIN + c16 * 8;
  }

  floatx4 acc[4][4];
#pragma unroll
  for (int i = 0; i < 4; ++i)
#pragma unroll
    for (int j = 0; j < 4; ++j) acc[i][j] = (floatx4){0.f, 0.f, 0.f, 0.f};

#define STAGE(KT, BUF)                                                          \
  do {                                                                          \
    const int _kt = (KT);                                                       \
    const int _rem = _kt % 18, _kh = _rem / 6, _r2 = _rem % 6;                  \
    const int _kw = _r2 >> 1, _ci0 = (_kt / 18) * 64 + (_r2 & 1) * 32;          \
    const int _bOff = (_kh * WP + _kw) * CIN + _ci0;                            \
    async_copy16(aSrc + (size_t)_kt * 16384, Ab[BUF] + wv * 2048);              \
    async_copy16(aSrc + (size_t)_kt * 16384 + 1024, Ab[BUF] + wv * 2048 + 1024);\
    async_copy16(bSrc[0] + _bOff, Bb[BUF] + wv * 2048);                         \
    async_copy16(bSrc[1] + _bOff, Bb[BUF] + wv * 2048 + 1024);                  \
  } while (0)

  STAGE(0, 0);   // prologue

#pragma unroll 2
  for (int kt = 0; kt < NCHUNK; ++kt) {
    const int buf = kt & 1;
    __syncthreads();                 // buffer `buf` ready; prior reads done
    if (kt + 1 < NCHUNK) STAGE(kt + 1, buf ^ 1);   // fire-and-forget for next iter

    short8 a[4], b[4];
#pragma unroll
    for (int i = 0; i < 4; ++i)
      a[i] = *(const short8*)(Ab[buf] + (waveM * 4 + i) * 1024 + lane * 16);
#pragma unroll
    for (int j = 0; j < 4; ++j)
      b[j] = *(const short8*)(Bb[buf] + (waveN * 64 + j * 16 + fm) * 64 + qx16);
#pragma unroll
    for (int i = 0; i < 4; ++i)
#pragma unroll
      for (int j = 0; j < 4; ++j)
        acc[i][j] = __builtin_amdgcn_mfma_f32_16x16x32_bf16(a[i], b[j], acc[i][j], 0, 0, 0);
  }
#undef STAGE

  // ---- epilogue: D col = lane&15 (n), row = (lane>>4)*4 + reg (m)
  const int col = lane & 15, quad = lane >> 4;
#pragma unroll
  for (int j = 0; j < 4; ++j) {
    const int n = n0 + waveN * 64 + j * 16 + col;
    const int bb = n / 3136, nr = n - bb * 3136;
    const size_t base = (size_t)bb * (COUT * 3136) + nr;
#pragma unroll
    for (int i = 0; i < 4; ++i) {
      const int co0 = m0 + waveM * 64 + i * 16 + quad * 4;
      const floatx4 b4 = *(const floatx4*)&bias[co0];
#pragma unroll
      for (int r = 0; r < 4; ++r) {
        y[base + (size_t)(co0 + r) * 3136] = acc[i][j][r] + b4[r];
      }
    }
  }
}

extern "C" void kernel_launch(void* const* d_in, const int* in_sizes, int n_in,
                              void* d_out, int out_size, void* d_ws, size_t ws_size,
                              hipStream_t stream) {
  const float* x = (const float*)d_in[0];
  const float* w = (const float*)d_in[1];
  const float* b = (const float*)d_in[2];
  float* y = (float*)d_out;

  // ws footprint: 27,541,504 + 589,824 = 28,131,328 B — identical to prior rounds
  const size_t xpad_bytes = (size_t)Bn * HP * ROWB * sizeof(__hip_bfloat16);
  __hip_bfloat16* xp  = (__hip_bfloat16*)d_ws;
  __hip_bfloat16* wtf = (__hip_bfloat16*)((char*)d_ws + xpad_bytes);

  prep<<<PREP_GRID, 256, 0, stream>>>(x, w, xp, wtf);
  conv_gemm<<<2 * ((Bn * Hh * Ww) / 128), 256, 0, stream>>>(wtf, xp, b, y);
}

// Round 5
// 210.265 us; speedup vs baseline: 1.0619x; 1.0005x over previous
//
#include <hip/hip_runtime.h>
#include <hip/hip_bf16.h>
#include <stdint.h>

// Problem constants
#define Bn   32
#define CIN  128
#define Hh   56
#define Ww   56
#define COUT 256
#define HP   58            // padded rows (1 top + 1 bottom)
#define WP   58            // padded width: 0=pad, 1..56 data, 57=pad
#define ROWB (WP*CIN)      // 7424 elements per padded row
#define NCHUNK 36          // K chunks of 32, order kt = hf*18 + kh*6 + kw*2 + c

// prep kernel block partition (all write-disjoint regions, single launch)
#define DATA_BLKS (Bn*Hh)                 // 1792: one (b,h) data row each
#define ZERO_BLKS (Bn)                    // 32: pad rows + side pad columns
#define WT_BLKS   96                      // (mb,hf,kh): 16*2*3 weight slabs
#define PREP_GRID (DATA_BLKS + ZERO_BLKS + WT_BLKS)

typedef __attribute__((ext_vector_type(8))) short short8;     // 8 x bf16
typedef __attribute__((ext_vector_type(4))) float floatx4;

__device__ __forceinline__ void async_copy16(const void* g, void* l) {
  // global -> LDS direct copy: GLOBAL address is PER-LANE; LDS dest =
  // wave-uniform base + lane*16.  [m104/m108]
  __builtin_amdgcn_global_load_lds(
      (const __attribute__((address_space(1))) uint32_t*)g,
      (__attribute__((address_space(3))) uint32_t*)l, 16, 0, 0);
}

__device__ __forceinline__ uint32_t pk2(float a, float b) {
  union { __hip_bfloat16 h; unsigned short u; } ca, cb;
  ca.h = __float2bfloat16(a);
  cb.h = __float2bfloat16(b);
  return (uint32_t)ca.u | ((uint32_t)cb.u << 16);
}

// ---------------------------------------------------------------------------
// prep: single launch replacing xform_x + xform_w (R1-verified, unchanged).
// ---------------------------------------------------------------------------
__global__ __launch_bounds__(256) void prep(const float* __restrict__ x,
                                            const float* __restrict__ w,
                                            __hip_bfloat16* __restrict__ xp,
                                            __hip_bfloat16* __restrict__ wtf) {
  __shared__ uint32_t t[HP * 65];   // 15080 B; weight path aliases as float[]
  const int bid = blockIdx.x, tid = threadIdx.x;

  if (bid < DATA_BLKS) {
    const int b = bid / Hh, h = bid % Hh;
    const float* xrow = x + (size_t)b * (CIN * Hh * Ww) + (size_t)h * Ww;
    for (int i = tid; i < 1024; i += 256) {
      const int wq = i & 15, cp = i >> 4;
      if (wq < 14) {
        const float* g0 = xrow + (size_t)(2 * cp) * (Hh * Ww) + wq * 4;
        const float4 v0 = *(const float4*)g0;
        const float4 v1 = *(const float4*)(g0 + Hh * Ww);
        const int r0 = (1 + 4 * wq) * 65 + cp;
        t[r0      ] = pk2(v0.x, v1.x);
        t[r0 +  65] = pk2(v0.y, v1.y);
        t[r0 + 130] = pk2(v0.z, v1.z);
        t[r0 + 195] = pk2(v0.w, v1.w);
      }
    }
    __syncthreads();
    const size_t obase = ((size_t)b * HP + (h + 1)) * ROWB;
    for (int i = tid; i < 896; i += 256) {
      const int wo = 1 + (i >> 4), cq = i & 15;
      const uint32_t* s = &t[wo * 65 + cq * 4];
      uint4 d; d.x = s[0]; d.y = s[1]; d.z = s[2]; d.w = s[3];
      *(uint4*)(xp + obase + (size_t)wo * CIN + cq * 8) = d;
    }
  } else if (bid < DATA_BLKS + ZERO_BLKS) {
    const int b = bid - DATA_BLKS;
    const uint4 z = {0u, 0u, 0u, 0u};
    uint4* r0  = (uint4*)(xp + (size_t)b * HP * ROWB);
    uint4* r57 = (uint4*)(xp + ((size_t)b * HP + (HP - 1)) * ROWB);
    for (int i = tid; i < ROWB / 8; i += 256) { r0[i] = z; r57[i] = z; }
    for (int i = tid; i < Hh * 32; i += 256) {      // 56 rows x (16+16) uint4
      const int hp = 1 + (i >> 5), s5 = i & 31;
      uint4* pr = (uint4*)(xp + ((size_t)b * HP + hp) * ROWB);
      pr[s5 < 16 ? s5 : (912 + s5 - 16)] = z;       // 912 = 57*128*2/16
    }
  } else {
    const int widx = bid - (DATA_BLKS + ZERO_BLKS);
    const int mb = widx / 6, t6 = widx % 6, hf = t6 / 3, kh = t6 % 3;
    float* s = (float*)t;                            // 3072 floats = 12 KB
    const float* wbase = w + (size_t)(mb * 16) * (CIN * 9) + hf * 576 + kh * 3;
    for (int idx = tid; idx < 3072; idx += 256) {    // s[m'][ci'][kw]
      const int mp = idx / 192, r2 = idx - mp * 192;
      const int cip = r2 / 3, p = r2 - cip * 3;
      s[idx] = wbase[(size_t)mp * (CIN * 9) + cip * 9 + p];
    }
    __syncthreads();
    uint32_t* wtfU = (uint32_t*)wtf;
    for (int k = 0; k < 6; ++k) {                    // 6 kt values: r = kw*2+c
      const int u = tid + k * 256;
      const int r = u >> 8, lane = (u >> 2) & 63, ep = u & 3;
      const int kw = r >> 1, c = r & 1;
      const int kt = hf * 18 + kh * 6 + r;
      const int fm = lane & 15, q = lane >> 4;
      const int cb = c * 32 + q * 8 + 2 * ep;        // ci' of even element
      const float v0 = s[fm * 192 + cb * 3 + kw];
      const float v1 = s[fm * 192 + (cb + 1) * 3 + kw];
      wtfU[(size_t)(kt * 16 + mb) * 256 + lane * 4 + ep] = pk2(v0, v1);
    }
  }
}

// ---------------------------------------------------------------------------
// Conv GEMM — R5: counted-vmcnt phase schedule (T3+T4+T5), designed for
// M=256. The 2-phase 128^2 structure plateaued at ~750 TF (R1/R4); rooflines
// are ~24us but we sit at 80us -> schedule-bound, not HW-bound.
//   Tile: BM=256 (all COUT) x BN=128 x BK=32. 512 thr = 8 waves (4M x 2N),
//   per-wave 64x64 output = acc[4][4] of 16x16x32 MFMA.
//   TRIPLE-buffered LDS (72KB: 3 x (16K A + 8K B)) -> 2 blocks/CU.
//   Per K-step t (36 steps):
//     s_waitcnt vmcnt(3)   // tile t resident; tile t+1's 3 loads in flight
//     s_barrier
//     STAGE(t+2 -> buf[(t+2)%3])   // 3 issues, fire-and-forget
//     8 x ds_read_b128 (A 4, B 4, T2-swizzled -> conflict-free)
//     s_barrier
//     setprio(1); 16 MFMA; setprio(0)
//   NO vmcnt(0) in the main loop (only final step). NO sched_barrier (R2's
//   m141-mode failure). Hazards audited: buf[(t+2)%3]'s readers drained
//   their ds_reads before their step-(t-1) MFMAs (data dep), which precede
//   this step's barrier; vmcnt(3)+barrier => tile t fully in LDS for all.
//   XCD swizzle: bn = (gid&7)*98 + (gid>>3) (bijective, 784=8*98); blocks
//   sharing input halo rows (consecutive bn) colocate on one XCD's L2.
// ---------------------------------------------------------------------------
__global__ __launch_bounds__(512, 4) void conv_gemm(const __hip_bfloat16* __restrict__ wtf,
                                                    const __hip_bfloat16* __restrict__ xp,
                                                    const float* __restrict__ bias,
                                                    float* __restrict__ y) {
  __shared__ __align__(16) char Ab[3][16384];  // [buf][mb 0..15][lane][16B]
  __shared__ __align__(16) char Bb[3][8192];   // [buf][pixel 0..127][64B swz]

  const int tid  = threadIdx.x;
  const int lane = tid & 63, wv = tid >> 6;          // 8 waves
  const int fm = lane & 15, q = lane >> 4;
  const int waveM = wv >> 1, waveN = wv & 1;         // 4M x 2N
  // T2 read-side swizzle (R2-verified, conflicts=0): 16B-unit q ^ ((fm>>1)&3)
  const int qx16 = (q ^ ((fm >> 1) & 3)) * 16;

  const int gid = blockIdx.x;                        // 784 blocks
  const int bn = (gid & 7) * 98 + (gid >> 3);        // bijective XCD-chunk swz
  const int n0 = bn * 128;

  // ---- A staging source: per-lane; A-tile = full wtf kt-chunk (16KB).
  const char* aSrcA = (const char*)wtf + wv * 1024 + lane * 16;

  // ---- B staging source: thread covers pixel sr=tid>>2, swizzled 16B unit.
  const int sr  = tid >> 2;
  const int n_r = n0 + sr;
  const int bimg = n_r / 3136, rr = n_r - bimg * 3136;
  const int hh = rr / 56, ww = rr - hh * 56;
  const int c16 = (tid & 3) ^ ((tid >> 3) & 3);      // write-side T2 involution
  const __hip_bfloat16* bSrc =
      xp + (size_t)((bimg * HP + hh) * WP + ww) * CIN + c16 * 8;

  floatx4 acc[4][4];
#pragma unroll
  for (int i = 0; i < 4; ++i)
#pragma unroll
    for (int j = 0; j < 4; ++j) acc[i][j] = (floatx4){0.f, 0.f, 0.f, 0.f};

#define STAGE(KT, BUF)                                                         \
  do {                                                                         \
    const int _kt = (KT);                                                      \
    const int _rem = _kt % 18, _kh = _rem / 6, _r2 = _rem % 6;                 \
    const int _kw = _r2 >> 1, _ci0 = (_kt / 18) * 64 + (_r2 & 1) * 32;         \
    const int _bOff = (_kh * WP + _kw) * CIN + _ci0;                           \
    async_copy16(aSrcA + (size_t)_kt * 16384,        Ab[BUF] + wv * 1024);     \
    async_copy16(aSrcA + (size_t)_kt * 16384 + 8192, Ab[BUF] + wv * 1024 + 8192); \
    async_copy16(bSrc + _bOff, Bb[BUF] + wv * 1024);                           \
  } while (0)

#define DSREAD(BT, A, B)                                                       \
  do {                                                                         \
    _Pragma("unroll")                                                          \
    for (int i = 0; i < 4; ++i)                                                \
      (A)[i] = *(const short8*)(Ab[BT] + (waveM * 4 + i) * 1024 + lane * 16);  \
    _Pragma("unroll")                                                          \
    for (int j = 0; j < 4; ++j)                                                \
      (B)[j] = *(const short8*)(Bb[BT] + (waveN * 64 + j * 16 + fm) * 64 + qx16); \
  } while (0)

#define MFMA16(A, B)                                                           \
  do {                                                                         \
    __builtin_amdgcn_s_setprio(1);                                             \
    _Pragma("unroll")                                                          \
    for (int i = 0; i < 4; ++i)                                                \
      _Pragma("unroll")                                                        \
      for (int j = 0; j < 4; ++j)                                              \
        acc[i][j] = __builtin_amdgcn_mfma_f32_16x16x32_bf16((A)[i], (B)[j],    \
                                                            acc[i][j], 0, 0, 0); \
    __builtin_amdgcn_s_setprio(0);                                             \
  } while (0)

  STAGE(0, 0);   // prologue: tiles 0,1 in flight (6 issues/thread)
  STAGE(1, 1);

#pragma unroll 3
  for (int t = 0; t < 34; ++t) {        // stages tiles 2..35
    asm volatile("s_waitcnt vmcnt(3)" ::: "memory");   // tile t landed
    __builtin_amdgcn_s_barrier();
    STAGE(t + 2, (t + 2) % 3);
    short8 a[4], b[4];
    DSREAD(t % 3, a, b);
    __builtin_amdgcn_s_barrier();
    MFMA16(a, b);
  }
  {                                     // t = 34: tile 35's 3 loads in flight
    asm volatile("s_waitcnt vmcnt(3)" ::: "memory");
    __builtin_amdgcn_s_barrier();
    short8 a[4], b[4];
    DSREAD(1, a, b);
    __builtin_amdgcn_s_barrier();
    MFMA16(a, b);
  }
  {                                     // t = 35: final drain
    asm volatile("s_waitcnt vmcnt(0)" ::: "memory");
    __builtin_amdgcn_s_barrier();
    short8 a[4], b[4];
    DSREAD(2, a, b);
    __builtin_amdgcn_s_barrier();
    MFMA16(a, b);
  }
#undef MFMA16
#undef DSREAD
#undef STAGE

  // ---- epilogue: D col = lane&15 (n), row = (lane>>4)*4 + reg (m)
  const int col = lane & 15, quad = lane >> 4;
#pragma unroll
  for (int j = 0; j < 4; ++j) {
    const int n = n0 + waveN * 64 + j * 16 + col;
    const int bb = n / 3136, nr = n - bb * 3136;
    const size_t base = (size_t)bb * (COUT * 3136) + nr;
#pragma unroll
    for (int i = 0; i < 4; ++i) {
      const int co0 = waveM * 64 + i * 16 + quad * 4;
      const floatx4 b4 = *(const floatx4*)&bias[co0];
#pragma unroll
      for (int r = 0; r < 4; ++r) {
        y[base + (size_t)(co0 + r) * 3136] = acc[i][j][r] + b4[r];
      }
    }
  }
}

extern "C" void kernel_launch(void* const* d_in, const int* in_sizes, int n_in,
                              void* d_out, int out_size, void* d_ws, size_t ws_size,
                              hipStream_t stream) {
  const float* x = (const float*)d_in[0];
  const float* w = (const float*)d_in[1];
  const float* b = (const float*)d_in[2];
  float* y = (float*)d_out;

  // ws footprint: 27,541,504 + 589,824 = 28,131,328 B — identical to prior rounds
  const size_t xpad_bytes = (size_t)Bn * HP * ROWB * sizeof(__hip_bfloat16);
  __hip_bfloat16* xp  = (__hip_bfloat16*)d_ws;
  __hip_bfloat16* wtf = (__hip_bfloat16*)((char*)d_ws + xpad_bytes);

  prep<<<PREP_GRID, 256, 0, stream>>>(x, w, xp, wtf);
  conv_gemm<<<(Bn * Hh * Ww) / 128, 512, 0, stream>>>(wtf, xp, b, y);
}

// Round 6
// 208.386 us; speedup vs baseline: 1.0715x; 1.0090x over previous
//
#include <hip/hip_runtime.h>
#include <hip/hip_bf16.h>
#include <stdint.h>

// Problem constants
#define Bn   32
#define CIN  128
#define Hh   56
#define Ww   56
#define COUT 256
#define HP   58            // padded rows (1 top + 1 bottom)
#define WP   58            // padded width: 0=pad, 1..56 data, 57=pad
#define ROWB (WP*CIN)      // 7424 elements per padded row
#define NCHUNK 36          // K chunks of 32, order kt = hf*18 + kh*6 + kw*2 + c

// prep kernel block partition (all write-disjoint regions, single launch)
#define DATA_BLKS (Bn*Hh)                 // 1792: one (b,h) data row each
#define ZERO_BLKS (Bn)                    // 32: pad rows + side pad columns
#define WT_BLKS   96                      // (mb,hf,kh): 16*2*3 weight slabs
#define PREP_GRID (DATA_BLKS + ZERO_BLKS + WT_BLKS)

typedef __attribute__((ext_vector_type(8))) short short8;     // 8 x bf16
typedef __attribute__((ext_vector_type(4))) float floatx4;

__device__ __forceinline__ void async_copy16(const void* g, void* l) {
  // global -> LDS direct copy: GLOBAL address is PER-LANE; LDS dest =
  // wave-uniform base + lane*16.  [m104/m108]
  __builtin_amdgcn_global_load_lds(
      (const __attribute__((address_space(1))) uint32_t*)g,
      (__attribute__((address_space(3))) uint32_t*)l, 16, 0, 0);
}

__device__ __forceinline__ uint32_t pk2(float a, float b) {
  union { __hip_bfloat16 h; unsigned short u; } ca, cb;
  ca.h = __float2bfloat16(a);
  cb.h = __float2bfloat16(b);
  return (uint32_t)ca.u | ((uint32_t)cb.u << 16);
}

// ---------------------------------------------------------------------------
// prep: single launch replacing xform_x + xform_w (R1-verified, unchanged).
// ---------------------------------------------------------------------------
__global__ __launch_bounds__(256) void prep(const float* __restrict__ x,
                                            const float* __restrict__ w,
                                            __hip_bfloat16* __restrict__ xp,
                                            __hip_bfloat16* __restrict__ wtf) {
  __shared__ uint32_t t[HP * 65];   // 15080 B; weight path aliases as float[]
  const int bid = blockIdx.x, tid = threadIdx.x;

  if (bid < DATA_BLKS) {
    const int b = bid / Hh, h = bid % Hh;
    const float* xrow = x + (size_t)b * (CIN * Hh * Ww) + (size_t)h * Ww;
    for (int i = tid; i < 1024; i += 256) {
      const int wq = i & 15, cp = i >> 4;
      if (wq < 14) {
        const float* g0 = xrow + (size_t)(2 * cp) * (Hh * Ww) + wq * 4;
        const float4 v0 = *(const float4*)g0;
        const float4 v1 = *(const float4*)(g0 + Hh * Ww);
        const int r0 = (1 + 4 * wq) * 65 + cp;
        t[r0      ] = pk2(v0.x, v1.x);
        t[r0 +  65] = pk2(v0.y, v1.y);
        t[r0 + 130] = pk2(v0.z, v1.z);
        t[r0 + 195] = pk2(v0.w, v1.w);
      }
    }
    __syncthreads();
    const size_t obase = ((size_t)b * HP + (h + 1)) * ROWB;
    for (int i = tid; i < 896; i += 256) {
      const int wo = 1 + (i >> 4), cq = i & 15;
      const uint32_t* s = &t[wo * 65 + cq * 4];
      uint4 d; d.x = s[0]; d.y = s[1]; d.z = s[2]; d.w = s[3];
      *(uint4*)(xp + obase + (size_t)wo * CIN + cq * 8) = d;
    }
  } else if (bid < DATA_BLKS + ZERO_BLKS) {
    const int b = bid - DATA_BLKS;
    const uint4 z = {0u, 0u, 0u, 0u};
    uint4* r0  = (uint4*)(xp + (size_t)b * HP * ROWB);
    uint4* r57 = (uint4*)(xp + ((size_t)b * HP + (HP - 1)) * ROWB);
    for (int i = tid; i < ROWB / 8; i += 256) { r0[i] = z; r57[i] = z; }
    for (int i = tid; i < Hh * 32; i += 256) {      // 56 rows x (16+16) uint4
      const int hp = 1 + (i >> 5), s5 = i & 31;
      uint4* pr = (uint4*)(xp + ((size_t)b * HP + hp) * ROWB);
      pr[s5 < 16 ? s5 : (912 + s5 - 16)] = z;       // 912 = 57*128*2/16
    }
  } else {
    const int widx = bid - (DATA_BLKS + ZERO_BLKS);
    const int mb = widx / 6, t6 = widx % 6, hf = t6 / 3, kh = t6 % 3;
    float* s = (float*)t;                            // 3072 floats = 12 KB
    const float* wbase = w + (size_t)(mb * 16) * (CIN * 9) + hf * 576 + kh * 3;
    for (int idx = tid; idx < 3072; idx += 256) {    // s[m'][ci'][kw]
      const int mp = idx / 192, r2 = idx - mp * 192;
      const int cip = r2 / 3, p = r2 - cip * 3;
      s[idx] = wbase[(size_t)mp * (CIN * 9) + cip * 9 + p];
    }
    __syncthreads();
    uint32_t* wtfU = (uint32_t*)wtf;
    for (int k = 0; k < 6; ++k) {                    // 6 kt values: r = kw*2+c
      const int u = tid + k * 256;
      const int r = u >> 8, lane = (u >> 2) & 63, ep = u & 3;
      const int kw = r >> 1, c = r & 1;
      const int kt = hf * 18 + kh * 6 + r;
      const int fm = lane & 15, q = lane >> 4;
      const int cb = c * 32 + q * 8 + 2 * ep;        // ci' of even element
      const float v0 = s[fm * 192 + cb * 3 + kw];
      const float v1 = s[fm * 192 + (cb + 1) * 3 + kw];
      wtfU[(size_t)(kt * 16 + mb) * 256 + lane * 4 + ep] = pk2(v0, v1);
    }
  }
}

// ---------------------------------------------------------------------------
// Conv GEMM — R6: R1's proven 2-phase 128x128 __syncthreads skeleton
// (78.5us; the two schedule ports R2/R5 both failed to beat it), with ONE
// orthogonal change: A NEVER TOUCHES LDS.
//   Arithmetic from R5 post-mortem: MFMA floor 28.5us + LDS traffic ~40us +
//   HBM write ~18us ~= the measured 84us -> LDS is the largest non-MFMA term.
//   wtf (576KB, fragment-ordered) is L2-resident on every XCD; each lane's
//   A-frag is a contiguous 16B at a computable address. Load A-frags straight
//   to VGPRs, parity-double-buffered (aReg[kt&1], compile-time-indexed under
//   unroll 2 -> no scratch, rule #20). The skeleton's __syncthreads drains
//   vmcnt anyway, so A(t+1) is guaranteed landed by the barrier that flips
//   the buffer -> latency hidden with ZERO new sync structure.
//   Effects: LDS traffic/block/step 88KB -> 40KB (-55%); LDS 32KB -> 16KB;
//   2 fewer gload_lds issues/thread/step.
//   B path: R1/R2-verified T2 both-sides swizzle (SQ_LDS_BANK_CONFLICT = 0).
// ---------------------------------------------------------------------------
__global__ __launch_bounds__(256, 4) void conv_gemm(const __hip_bfloat16* __restrict__ wtf,
                                                    const __hip_bfloat16* __restrict__ xp,
                                                    const float* __restrict__ bias,
                                                    float* __restrict__ y) {
  __shared__ __align__(16) char Bb[2][8192];   // [buf][pixel 0..127][64B swz]

  const int tid  = threadIdx.x;
  const int lane = tid & 63, wv = tid >> 6;
  const int fm = lane & 15, q = lane >> 4;
  const int waveM = wv & 1, waveN = wv >> 1;
  // T2 read-side swizzle (R2-verified, conflicts=0): 16B-unit q ^ ((fm>>1)&3)
  const int qx16 = (q ^ ((fm >> 1) & 3)) * 16;

  // XCD swizzle: gid, gid+8 share bn (same B tile) on one XCD. Bijective/1568.
  const int gid = blockIdx.x;
  const int bm = (gid >> 3) & 1;
  const int bn = (gid & 7) | ((gid >> 4) << 3);   // [0,784)
  const int m0 = bm * 128, n0 = bn * 128;

  // ---- A source: direct global->VGPR. Frag i of this wave at chunk kt:
  //   wtf + kt*16384 + (8*bm + waveM*4 + i)*1024 + lane*16
  const char* aBase = (const char*)wtf + (size_t)(8 * bm + waveM * 4) * 1024 + lane * 16;

  // ---- B staging sources: 2 pixel-groups of 16 per wave. T2 write-side
  // swizzle of the GLOBAL 16B-unit by ((lane>>3)&3); LDS dest stays linear
  // (global_load_lds requirement, m104). Same involution as the read side.
  const __hip_bfloat16* bSrc[2];
#pragma unroll
  for (int c = 0; c < 2; ++c) {
    const int sr = wv * 32 + c * 16 + (lane >> 2);     // pixel row in tile
    const int n_r = n0 + sr;
    const int b = n_r / 3136, r = n_r - b * 3136, h = r / 56, w = r - h * 56;
    const int c16 = (lane & 3) ^ ((lane >> 3) & 3);    // swizzled 16B unit
    bSrc[c] = xp + (size_t)((b * HP + h) * WP + w) * CIN + c16 * 8;
  }

  floatx4 acc[4][4];
#pragma unroll
  for (int i = 0; i < 4; ++i)
#pragma unroll
    for (int j = 0; j < 4; ++j) acc[i][j] = (floatx4){0.f, 0.f, 0.f, 0.f};

#define STAGE_B(KT, BUF)                                                        \
  do {                                                                          \
    const int _kt = (KT);                                                       \
    const int _rem = _kt % 18, _kh = _rem / 6, _r2 = _rem % 6;                  \
    const int _kw = _r2 >> 1, _ci0 = (_kt / 18) * 64 + (_r2 & 1) * 32;          \
    const int _bOff = (_kh * WP + _kw) * CIN + _ci0;                            \
    async_copy16(bSrc[0] + _bOff, Bb[BUF] + wv * 2048);                         \
    async_copy16(bSrc[1] + _bOff, Bb[BUF] + wv * 2048 + 1024);                  \
  } while (0)

#define LOADA(KT, DST)                                                          \
  do {                                                                          \
    const char* _ag = aBase + (size_t)(KT) * 16384;                             \
    _Pragma("unroll")                                                           \
    for (int i = 0; i < 4; ++i) (DST)[i] = *(const short8*)(_ag + i * 1024);    \
  } while (0)

  short8 aReg[2][4];          // parity double-buffer; indices compile-time
  LOADA(0, aReg[0]);          // prologue: A(0) in flight to regs
  STAGE_B(0, 0);              // prologue: B(0) in flight to LDS

#pragma unroll 2
  for (int kt = 0; kt < NCHUNK; ++kt) {
    const int buf = kt & 1;
    __syncthreads();          // drains vmcnt: B(kt) in LDS, aReg[kt&1] landed
    if (kt + 1 < NCHUNK) {
      STAGE_B(kt + 1, buf ^ 1);        // fire-and-forget for next iter
      LOADA(kt + 1, aReg[(kt + 1) & 1]);
    }
    short8 b[4];
#pragma unroll
    for (int j = 0; j < 4; ++j)
      b[j] = *(const short8*)(Bb[buf] + (waveN * 64 + j * 16 + fm) * 64 + qx16);
#pragma unroll
    for (int i = 0; i < 4; ++i)
#pragma unroll
      for (int j = 0; j < 4; ++j)
        acc[i][j] = __builtin_amdgcn_mfma_f32_16x16x32_bf16(aReg[kt & 1][i], b[j],
                                                            acc[i][j], 0, 0, 0);
  }
#undef LOADA
#undef STAGE_B

  // ---- epilogue: D col = lane&15 (n), row = (lane>>4)*4 + reg (m)
  const int col = lane & 15, quad = lane >> 4;
#pragma unroll
  for (int j = 0; j < 4; ++j) {
    const int n = n0 + waveN * 64 + j * 16 + col;
    const int bb = n / 3136, nr = n - bb * 3136;
    const size_t base = (size_t)bb * (COUT * 3136) + nr;
#pragma unroll
    for (int i = 0; i < 4; ++i) {
      const int co0 = m0 + waveM * 64 + i * 16 + quad * 4;
      const floatx4 b4 = *(const floatx4*)&bias[co0];
#pragma unroll
      for (int r = 0; r < 4; ++r) {
        y[base + (size_t)(co0 + r) * 3136] = acc[i][j][r] + b4[r];
      }
    }
  }
}

extern "C" void kernel_launch(void* const* d_in, const int* in_sizes, int n_in,
                              void* d_out, int out_size, void* d_ws, size_t ws_size,
                              hipStream_t stream) {
  const float* x = (const float*)d_in[0];
  const float* w = (const float*)d_in[1];
  const float* b = (const float*)d_in[2];
  float* y = (float*)d_out;

  // ws footprint: 27,541,504 + 589,824 = 28,131,328 B — identical to prior rounds
  const size_t xpad_bytes = (size_t)Bn * HP * ROWB * sizeof(__hip_bfloat16);
  __hip_bfloat16* xp  = (__hip_bfloat16*)d_ws;
  __hip_bfloat16* wtf = (__hip_bfloat16*)((char*)d_ws + xpad_bytes);

  prep<<<PREP_GRID, 256, 0, stream>>>(x, w, xp, wtf);
  conv_gemm<<<2 * ((Bn * Hh * Ww) / 128), 256, 0, stream>>>(wtf, xp, b, y);
}